// Round 3
// baseline (452.030 us; speedup 1.0000x reference)
//
#include <hip/hip_runtime.h>
#include <hip/hip_bf16.h>
#include <stdint.h>

#define DM 1024
#define DF 2048
#define NTOK 8192

typedef float f32x4 __attribute__((ext_vector_type(4)));
typedef short s16x8 __attribute__((ext_vector_type(8)));   // 8 bf16 in 4 VGPRs

__device__ __forceinline__ unsigned short f2bf(float f) {
    union { float f; unsigned int u; } v; v.f = f;
    unsigned int r = v.u + 0x7fffu + ((v.u >> 16) & 1u);   // RNE
    return (unsigned short)(r >> 16);
}

// ---------------- kernel 1: fused (a) w1/w2 -> bf16 transposed, (b) zero-out + gate + x->bf16 ----------------
// blocks [0,4096): weight transpose tiles; blocks [4096,6144): per-token gating (4 tokens/block)
__global__ __launch_bounds__(256) void prep_cvt_kernel(const float* __restrict__ x,
                                                       const float* __restrict__ gw,
                                                       const float* __restrict__ gb,
                                                       const float* __restrict__ w1,
                                                       const float* __restrict__ w2,
                                                       unsigned short* __restrict__ xb,
                                                       unsigned short* __restrict__ w1t,
                                                       unsigned short* __restrict__ w2t,
                                                       float* __restrict__ out,
                                                       int* __restrict__ counts,
                                                       int* __restrict__ lists,
                                                       float* __restrict__ sls) {
    __shared__ float tile[64][65];
    if (blockIdx.x < 4096) {
        // ---- weight transpose: fp32 [k][n] -> bf16 [n][k], experts {0,1} ----
        const int b = blockIdx.x;
        const int z = b >> 10;            // 0,1: w1 e0/e1 ; 2,3: w2 e0/e1
        const int rem = b & 1023;
        const int by = rem >> 5, bx = rem & 31;
        const int e = z & 1, is2 = z >> 1;
        const int R = is2 ? DF : DM;      // src rows (k)
        const int C = is2 ? DM : DF;      // src cols (n)
        const int r0 = by * 64, c0 = bx * 64;
        if (r0 >= R || c0 >= C) return;
        const float* src = is2 ? (w2 + (size_t)e * DF * DM) : (w1 + (size_t)e * DM * DF);
        unsigned short* dst = is2 ? (w2t + (size_t)e * DM * DF) : (w1t + (size_t)e * DM * DF);
        const int tc = threadIdx.x & 63;
        const int tr = threadIdx.x >> 6;
        for (int rr = tr; rr < 64; rr += 4)
            tile[rr][tc] = src[(size_t)(r0 + rr) * C + (c0 + tc)];
        __syncthreads();
        for (int rr = tr; rr < 64; rr += 4)
            dst[(size_t)(c0 + rr) * R + (r0 + tc)] = f2bf(tile[tc][rr]);
        return;
    }
    // ---- gating + zero-out + selective x->bf16 (1 wave/token) ----
    const int bid = blockIdx.x - 4096;
    const int wv = threadIdx.x >> 6, lane = threadIdx.x & 63;
    const int t = bid * 4 + wv;
    const float* xr = x + (size_t)t * DM;
    float* outr = out + (size_t)t * DM;
    float acc[8];
#pragma unroll
    for (int e = 0; e < 8; ++e) acc[e] = 0.f;
    float4 xv[4];
    const float4 z4 = make_float4(0.f, 0.f, 0.f, 0.f);
#pragma unroll
    for (int i = 0; i < 4; ++i) {
        const int c4 = i * 64 + lane;                 // float4 index within the 256-float4 row
        xv[i] = ((const float4*)xr)[c4];
        ((float4*)outr)[c4] = z4;
        const float xs[4] = {xv[i].x, xv[i].y, xv[i].z, xv[i].w};
        const float* g = gw + (size_t)c4 * 32;
#pragma unroll
        for (int jj = 0; jj < 4; ++jj) {
            float4 ga = ((const float4*)(g + jj * 8))[0];
            float4 gbv = ((const float4*)(g + jj * 8 + 4))[0];
            acc[0] += xs[jj] * ga.x;  acc[1] += xs[jj] * ga.y;
            acc[2] += xs[jj] * ga.z;  acc[3] += xs[jj] * ga.w;
            acc[4] += xs[jj] * gbv.x; acc[5] += xs[jj] * gbv.y;
            acc[6] += xs[jj] * gbv.z; acc[7] += xs[jj] * gbv.w;
        }
    }
#pragma unroll
    for (int off = 32; off > 0; off >>= 1) {
#pragma unroll
        for (int e = 0; e < 8; ++e) acc[e] += __shfl_xor(acc[e], off, 64);
    }
    // every lane has the full sums now
    float lg[8];
#pragma unroll
    for (int e = 0; e < 8; ++e) lg[e] = acc[e] + gb[e];
    int b1i = 0; float b1v = lg[0];
#pragma unroll
    for (int e = 1; e < 8; ++e) if (lg[e] > b1v) { b1v = lg[e]; b1i = e; }
    int b2i = -1; float b2v = -3.4e38f;
#pragma unroll
    for (int e = 0; e < 8; ++e) if (e != b1i && lg[e] > b2v) { b2v = lg[e]; b2i = e; }
    const bool sel = (b1i == 0) || (b2i == 1);
    if (sel) {        // only selected tokens are ever gathered by the GEMMs
        unsigned short* xbr = xb + (size_t)t * DM;
#pragma unroll
        for (int i = 0; i < 4; ++i) {
            const int c4 = i * 64 + lane;
            ushort4 o;
            o.x = f2bf(xv[i].x); o.y = f2bf(xv[i].y); o.z = f2bf(xv[i].z); o.w = f2bf(xv[i].w);
            ((ushort4*)xbr)[c4] = o;
        }
    }
    if (lane == 0) {
        float den = 0.f;
#pragma unroll
        for (int e = 0; e < 8; ++e) den += expf(lg[e] - b1v);
        if (b1i == 0) {                       // top-1 slot matches expert 0
            float s0 = expf(lg[0] - b1v) / den;
            int p = atomicAdd(&counts[0], 1);
            lists[p] = t; sls[p] = s0;
        }
        if (b2i == 1) {                       // top-2 slot matches expert 1
            float s1 = expf(lg[1] - b1v) / den;
            int p = atomicAdd(&counts[1], 1);
            lists[NTOK + p] = t; sls[NTOK + p] = s1;
        }
    }
    if (bid == 0 && threadIdx.x == 0) out[(size_t)NTOK * DM] = 0.0f;  // lbl == 0 exactly
}

// ---------------- kernels 2/3: MFMA GEMM, 64x64 tile, BK=64, reg->LDS double buffer ----------------
// STAGE2=false: h = gelu(Xg @ W1 + b1) -> hout (bf16 [Ne][DF])
// STAGE2=true : out[tok] += scale * (h @ W2 + b2), split-K, fp32 atomicAdd scatter
template <bool STAGE2, int SPLIT>
__global__ __launch_bounds__(256, 4) void moe_gemm(const unsigned short* __restrict__ Aglob,
                                                   const unsigned short* __restrict__ Bglob,
                                                   const float* __restrict__ bias,
                                                   unsigned short* __restrict__ hout,
                                                   float* __restrict__ outp,
                                                   const int* __restrict__ counts,
                                                   const int* __restrict__ lists,
                                                   const float* __restrict__ sls) {
    constexpr int KTOT = STAGE2 ? DF : DM;
    constexpr int KS = KTOT / SPLIT;      // k span per block
    constexpr int NS = KS / 64;           // k-steps of 64
    const int z = blockIdx.z;
    const int e = z / SPLIT, ksp = z % SPLIT;
    const int Ne = counts[e];
    const int m0 = blockIdx.y * 64;
    if (m0 >= Ne) return;
    const int n0 = blockIdx.x * 64;
    const int k0 = ksp * KS;
    const int tid = threadIdx.x;
    const int lane = tid & 63, wv = tid >> 6;
    const int wr = wv >> 1, wc = wv & 1;           // 2x2 wave grid; wave owns 32x32
    const int lm = lane & 15, qk = lane >> 4;

    const int* list = lists + e * NTOK;
    const unsigned short* Ae = STAGE2 ? (Aglob + (size_t)e * NTOK * DF) : Aglob;
    const unsigned short* Be = Bglob + (size_t)e * DM * DF;

    __shared__ alignas(16) unsigned short As[64 * 64];   // [row][slot^ (row&7)] 16B chunks
    __shared__ alignas(16) unsigned short Bs[64 * 64];

    // per-thread staging: 2 chunks of A tile + 2 of B tile (64 rows x 8 chunks = 512 chunks)
    const unsigned short* srcA[2];
    const unsigned short* srcB[2];
    int slotA[2], slotB[2];
#pragma unroll
    for (int r = 0; r < 2; ++r) {
        int c = tid + r * 256;
        int row = c >> 3, q = c & 7;
        int rg = m0 + row;
        if (rg >= Ne) rg = m0;                      // clamp: valid data, epilogue-guarded
        size_t arow = STAGE2 ? (size_t)rg * KTOT : (size_t)list[rg] * KTOT;
        srcA[r] = Ae + arow + k0 + q * 8;
        slotA[r] = row * 8 + (q ^ (row & 7));       // XOR swizzle -> conflict-free b128 reads
        srcB[r] = Be + (size_t)(n0 + row) * KTOT + k0 + q * 8;
        slotB[r] = slotA[r] - row * 8 + row * 8;    // same formula
        slotB[r] = row * 8 + (q ^ (row & 7));
    }

    f32x4 acc[2][2];
#pragma unroll
    for (int i = 0; i < 2; ++i)
#pragma unroll
        for (int j = 0; j < 2; ++j) acc[i][j] = (f32x4){0.f, 0.f, 0.f, 0.f};

    uint4 pa[2], pb[2];
    auto gload = [&]() {
#pragma unroll
        for (int r = 0; r < 2; ++r) {
            pa[r] = *(const uint4*)srcA[r]; srcA[r] += 64;
            pb[r] = *(const uint4*)srcB[r]; srcB[r] += 64;
        }
    };
    auto lwrite = [&]() {
#pragma unroll
        for (int r = 0; r < 2; ++r) {
            *(uint4*)&As[slotA[r] * 8] = pa[r];
            *(uint4*)&Bs[slotB[r] * 8] = pb[r];
        }
    };
    auto compute = [&]() {
#pragma unroll
        for (int h = 0; h < 2; ++h) {               // two 16x16x32 k-halves of BK=64
            s16x8 af[2], bf[2];
#pragma unroll
            for (int am = 0; am < 2; ++am) {
                int rA = wr * 32 + am * 16 + lm;
                int sl = (h * 4 + qk) ^ (rA & 7);
                af[am] = *(const s16x8*)&As[rA * 64 + sl * 8];
            }
#pragma unroll
            for (int bn = 0; bn < 2; ++bn) {
                int rB = wc * 32 + bn * 16 + lm;
                int sl = (h * 4 + qk) ^ (rB & 7);
                bf[bn] = *(const s16x8*)&Bs[rB * 64 + sl * 8];
            }
#pragma unroll
            for (int am = 0; am < 2; ++am)
#pragma unroll
                for (int bn = 0; bn < 2; ++bn)
                    acc[am][bn] = __builtin_amdgcn_mfma_f32_16x16x32_bf16(af[am], bf[bn], acc[am][bn], 0, 0, 0);
        }
    };

    gload();            // tile 0 -> regs
    lwrite();           // regs -> LDS (compiler waits vmcnt here)
    __syncthreads();
#pragma unroll 1
    for (int s = 0; s < NS - 1; ++s) {
        gload();        // prefetch tile s+1; stays in flight through compute()
        compute();
        __syncthreads();
        lwrite();
        __syncthreads();
    }
    compute();

    if (!STAGE2) {
        const float* be = bias + e * DF;
        unsigned short* he = hout + (size_t)e * NTOK * DF;
#pragma unroll
        for (int am = 0; am < 2; ++am) {
#pragma unroll
            for (int bn = 0; bn < 2; ++bn) {
                int ng = n0 + wc * 32 + bn * 16 + lm;        // C/D: col = lane&15
                float bb = be[ng];
                f32x4 v = acc[am][bn];
#pragma unroll
                for (int r = 0; r < 4; ++r) {
                    int ml = wr * 32 + am * 16 + qk * 4 + r; // C/D: row = (lane>>4)*4+reg
                    int rg = m0 + ml;
                    if (rg < Ne) {
                        float tpre = v[r] + bb;
                        float g = 0.5f * tpre * (1.0f + erff(tpre * 0.70710678118654752f));
                        he[(size_t)rg * DF + ng] = f2bf(g);
                    }
                }
            }
        }
    } else {
        const float* be = bias + e * DM;
        const float* sl = sls + e * NTOK;
#pragma unroll
        for (int am = 0; am < 2; ++am) {
#pragma unroll
            for (int bn = 0; bn < 2; ++bn) {
                int ng = n0 + wc * 32 + bn * 16 + lm;
                float bb = (ksp == 0) ? be[ng] : 0.0f;       // bias added by split 0 only
                f32x4 v = acc[am][bn];
#pragma unroll
                for (int r = 0; r < 4; ++r) {
                    int ml = wr * 32 + am * 16 + qk * 4 + r;
                    int rg = m0 + ml;
                    if (rg < Ne) {
                        int tok = list[rg];
                        float s = sl[rg];
                        atomicAdd(&outp[(size_t)tok * DM + ng], s * (v[r] + bb));
                    }
                }
            }
        }
    }
}

extern "C" void kernel_launch(void* const* d_in, const int* in_sizes, int n_in,
                              void* d_out, int out_size, void* d_ws, size_t ws_size,
                              hipStream_t stream) {
    const float* x  = (const float*)d_in[0];
    const float* gw = (const float*)d_in[1];
    const float* gb = (const float*)d_in[2];
    const float* w1 = (const float*)d_in[3];
    const float* b1 = (const float*)d_in[4];
    const float* w2 = (const float*)d_in[5];
    const float* b2 = (const float*)d_in[6];
    float* out = (float*)d_out;
    char* ws = (char*)d_ws;

    // ws layout (bytes): [0] counts, [1024] lists[2][8192], [66560] sls[2][8192],
    // [262144] xb bf16[8192*1024], [+16MiB] w1t bf16[2][2048][1024],
    // [+8MiB] w2t bf16[2][1024][2048], [+8MiB] h bf16[2][8192][2048].  Total ~96.3 MB.
    int*            counts = (int*)(ws + 0);
    int*            lists  = (int*)(ws + 1024);
    float*          sls    = (float*)(ws + 1024 + 65536);
    unsigned short* xb     = (unsigned short*)(ws + 262144);
    unsigned short* w1t    = (unsigned short*)(ws + 262144 + 16777216);
    unsigned short* w2t    = (unsigned short*)(ws + 262144 + 16777216 + 8388608);
    unsigned short* hbuf   = (unsigned short*)(ws + 262144 + 16777216 + 16777216);

    hipMemsetAsync(counts, 0, 8, stream);
    prep_cvt_kernel<<<4096 + NTOK / 4, 256, 0, stream>>>(x, gw, gb, w1, w2, xb, w1t, w2t,
                                                         out, counts, lists, sls);
    // stage 1: per expert, M up to NTOK (ghost blocks exit on counts), N=DF, K=DM
    moe_gemm<false, 1><<<dim3(DF / 64, NTOK / 64, 2), 256, 0, stream>>>(xb, w1t, b1, hbuf, nullptr, counts, lists, sls);
    // stage 2: split-K x2 for 2x blocks
    moe_gemm<true, 2><<<dim3(DM / 64, NTOK / 64, 4), 256, 0, stream>>>(hbuf, w2t, b2, nullptr, out, counts, lists, sls);
}

// Round 4
// 269.087 us; speedup vs baseline: 1.6799x; 1.6799x over previous
//
#include <hip/hip_runtime.h>
#include <hip/hip_bf16.h>
#include <stdint.h>

#define DM 1024
#define DF 2048
#define NTOK 8192

typedef float f32x4 __attribute__((ext_vector_type(4)));
typedef short s16x8 __attribute__((ext_vector_type(8)));   // 8 bf16 in 4 VGPRs

__device__ __forceinline__ unsigned short f2bf(float f) {
    union { float f; unsigned int u; } v; v.f = f;
    unsigned int r = v.u + 0x7fffu + ((v.u >> 16) & 1u);   // RNE
    return (unsigned short)(r >> 16);
}

__device__ __forceinline__ void gload_lds16(const void* g, void* l) {
    __builtin_amdgcn_global_load_lds(
        (const __attribute__((address_space(1))) unsigned int*)g,
        (__attribute__((address_space(3))) unsigned int*)l, 16, 0, 0);
}

// ---------------- kernel 1: fused (a) w1/w2 -> bf16 transposed, (b) zero-out + gate + x->bf16 ----------------
// blocks [0,4096): weight transpose tiles; blocks [4096,6144): per-token gating (4 tokens/block)
__global__ __launch_bounds__(256) void prep_cvt_kernel(const float* __restrict__ x,
                                                       const float* __restrict__ gw,
                                                       const float* __restrict__ gb,
                                                       const float* __restrict__ w1,
                                                       const float* __restrict__ w2,
                                                       unsigned short* __restrict__ xb,
                                                       unsigned short* __restrict__ w1t,
                                                       unsigned short* __restrict__ w2t,
                                                       float* __restrict__ out,
                                                       int* __restrict__ counts,
                                                       int* __restrict__ lists,
                                                       float* __restrict__ sls) {
    __shared__ float tile[64][65];
    if (blockIdx.x < 4096) {
        // ---- weight transpose: fp32 [k][n] -> bf16 [n][k], experts {0,1} ----
        const int b = blockIdx.x;
        const int z = b >> 10;            // 0,1: w1 e0/e1 ; 2,3: w2 e0/e1
        const int rem = b & 1023;
        const int by = rem >> 5, bx = rem & 31;
        const int e = z & 1, is2 = z >> 1;
        const int R = is2 ? DF : DM;      // src rows (k)
        const int C = is2 ? DM : DF;      // src cols (n)
        const int r0 = by * 64, c0 = bx * 64;
        if (r0 >= R || c0 >= C) return;
        const float* src = is2 ? (w2 + (size_t)e * DF * DM) : (w1 + (size_t)e * DM * DF);
        unsigned short* dst = is2 ? (w2t + (size_t)e * DM * DF) : (w1t + (size_t)e * DM * DF);
        const int tc = threadIdx.x & 63;
        const int tr = threadIdx.x >> 6;
        for (int rr = tr; rr < 64; rr += 4)
            tile[rr][tc] = src[(size_t)(r0 + rr) * C + (c0 + tc)];
        __syncthreads();
        for (int rr = tr; rr < 64; rr += 4)
            dst[(size_t)(c0 + rr) * R + (r0 + tc)] = f2bf(tile[tc][rr]);
        return;
    }
    // ---- gating + zero-out + selective x->bf16 (1 wave/token) ----
    const int bid = blockIdx.x - 4096;
    const int wv = threadIdx.x >> 6, lane = threadIdx.x & 63;
    const int t = bid * 4 + wv;
    const float* xr = x + (size_t)t * DM;
    float* outr = out + (size_t)t * DM;
    float acc[8];
#pragma unroll
    for (int e = 0; e < 8; ++e) acc[e] = 0.f;
    float4 xv[4];
    const float4 z4 = make_float4(0.f, 0.f, 0.f, 0.f);
#pragma unroll
    for (int i = 0; i < 4; ++i) {
        const int c4 = i * 64 + lane;                 // float4 index within the 256-float4 row
        xv[i] = ((const float4*)xr)[c4];
        ((float4*)outr)[c4] = z4;
        const float xs[4] = {xv[i].x, xv[i].y, xv[i].z, xv[i].w};
        const float* g = gw + (size_t)c4 * 32;
#pragma unroll
        for (int jj = 0; jj < 4; ++jj) {
            float4 ga = ((const float4*)(g + jj * 8))[0];
            float4 gbv = ((const float4*)(g + jj * 8 + 4))[0];
            acc[0] += xs[jj] * ga.x;  acc[1] += xs[jj] * ga.y;
            acc[2] += xs[jj] * ga.z;  acc[3] += xs[jj] * ga.w;
            acc[4] += xs[jj] * gbv.x; acc[5] += xs[jj] * gbv.y;
            acc[6] += xs[jj] * gbv.z; acc[7] += xs[jj] * gbv.w;
        }
    }
#pragma unroll
    for (int off = 32; off > 0; off >>= 1) {
#pragma unroll
        for (int e = 0; e < 8; ++e) acc[e] += __shfl_xor(acc[e], off, 64);
    }
    // every lane has the full sums now
    float lg[8];
#pragma unroll
    for (int e = 0; e < 8; ++e) lg[e] = acc[e] + gb[e];
    int b1i = 0; float b1v = lg[0];
#pragma unroll
    for (int e = 1; e < 8; ++e) if (lg[e] > b1v) { b1v = lg[e]; b1i = e; }
    int b2i = -1; float b2v = -3.4e38f;
#pragma unroll
    for (int e = 0; e < 8; ++e) if (e != b1i && lg[e] > b2v) { b2v = lg[e]; b2i = e; }
    const bool sel = (b1i == 0) || (b2i == 1);
    if (sel) {        // only selected tokens are ever gathered by the GEMMs
        unsigned short* xbr = xb + (size_t)t * DM;
#pragma unroll
        for (int i = 0; i < 4; ++i) {
            const int c4 = i * 64 + lane;
            ushort4 o;
            o.x = f2bf(xv[i].x); o.y = f2bf(xv[i].y); o.z = f2bf(xv[i].z); o.w = f2bf(xv[i].w);
            ((ushort4*)xbr)[c4] = o;
        }
    }
    if (lane == 0) {
        float den = 0.f;
#pragma unroll
        for (int e = 0; e < 8; ++e) den += expf(lg[e] - b1v);
        if (b1i == 0) {                       // top-1 slot matches expert 0
            float s0 = expf(lg[0] - b1v) / den;
            int p = atomicAdd(&counts[0], 1);
            lists[p] = t; sls[p] = s0;
        }
        if (b2i == 1) {                       // top-2 slot matches expert 1
            float s1 = expf(lg[1] - b1v) / den;
            int p = atomicAdd(&counts[1], 1);
            lists[NTOK + p] = t; sls[NTOK + p] = s1;
        }
    }
    if (bid == 0 && threadIdx.x == 0) out[(size_t)NTOK * DM] = 0.0f;  // lbl == 0 exactly
}

// ---------------- kernels 2/3: MFMA GEMM, 64x64 tile, BK=128, global_load_lds staging ----------------
// Latency-chain design: only K/128 (=8) drain points per block; whole GEMM co-resident
// (1024 active blocks = 4/CU at 32 KB LDS), so kernel wall ~= one block's chain.
// 1-D grid bid = m*64 + g; bid%8 (XCD) is a function of (n-tile,expert) for L2 locality.
// STAGE2=false: h = gelu(Xg @ W1 + b1) -> hout (bf16 [e][NTOK][DF])
// STAGE2=true : out[tok] += scale * (h @ W2 + b2), split-K=2, fp32 atomicAdd scatter
template <bool STAGE2>
__global__ __launch_bounds__(256) void moe_gemm(const unsigned short* __restrict__ Aglob,
                                                const unsigned short* __restrict__ Bglob,
                                                const float* __restrict__ bias,
                                                unsigned short* __restrict__ hout,
                                                float* __restrict__ outp,
                                                const int* __restrict__ counts,
                                                const int* __restrict__ lists,
                                                const float* __restrict__ sls) {
    constexpr int KTOT = STAGE2 ? DF : DM;
    constexpr int KS = STAGE2 ? KTOT / 2 : KTOT;   // split-K=2 on stage 2
    constexpr int NS = KS / 128;                   // 8 k-steps
    const int bid = blockIdx.x;
    const int g = bid & 63;
    const int m0 = (bid >> 6) * 64;
    const int n_idx = STAGE2 ? (g >> 2) : (g >> 1);
    const int e     = STAGE2 ? ((g >> 1) & 1) : (g & 1);
    const int ksp   = STAGE2 ? (g & 1) : 0;
    const int Ne = counts[e];
    if (m0 >= Ne) return;
    const int n0 = n_idx * 64;
    const int k0 = ksp * KS;
    const int tid = threadIdx.x;
    const int lane = tid & 63, wv = tid >> 6;
    const int wr = wv >> 1, wc = wv & 1;           // 2x2 wave grid; wave owns 32x32
    const int lm = lane & 15, qk = lane >> 4;

    const int* list = lists + e * NTOK;
    const unsigned short* Ae = STAGE2 ? (Aglob + (size_t)e * NTOK * DF) : Aglob;
    const unsigned short* Be = Bglob + (size_t)e * DM * DF;

    __shared__ alignas(16) unsigned short As[64 * 128];   // 16 KB, [row][16 chunks of 16B]
    __shared__ alignas(16) unsigned short Bs[64 * 128];   // 16 KB

    // Thread stages LDS slot c = tid + r*256 (forced: slot byte addr = c*16).
    // Source chunk q = (c&15) ^ ((row>>1)&7): 3-bit XOR swizzle -> b128 reads hit
    // 8 distinct bank groups (2 lanes each per phase) = conflict-free.
    const unsigned short* srcA[4];
    const unsigned short* srcB[4];
#pragma unroll
    for (int r = 0; r < 4; ++r) {
        int c = tid + r * 256;
        int row = c >> 4;
        int q = (c & 15) ^ ((row >> 1) & 7);
        int rg = m0 + row;
        if (rg >= Ne) rg = m0;                      // clamp: valid data, epilogue-guarded
        size_t arow = STAGE2 ? (size_t)rg * KTOT : (size_t)list[rg] * KTOT;
        srcA[r] = Ae + arow + k0 + q * 8;
        srcB[r] = Be + (size_t)(n0 + row) * KTOT + k0 + q * 8;
    }

    f32x4 acc[2][2];
#pragma unroll
    for (int i = 0; i < 2; ++i)
#pragma unroll
        for (int j = 0; j < 2; ++j) acc[i][j] = (f32x4){0.f, 0.f, 0.f, 0.f};

#pragma unroll 1
    for (int s = 0; s < NS; ++s) {
#pragma unroll
        for (int r = 0; r < 4; ++r) {               // stage tile s (A 16 KB + B 16 KB)
            gload_lds16(srcA[r], &As[(r * 256 + wv * 64) * 8]);
            gload_lds16(srcB[r], &Bs[(r * 256 + wv * 64) * 8]);
            srcA[r] += 128; srcB[r] += 128;
        }
        __syncthreads();                            // drains DMA (vmcnt 0)
#pragma unroll
        for (int h = 0; h < 4; ++h) {               // four 16x16x32 k-slices of BK=128
            s16x8 af[2], bf[2];
#pragma unroll
            for (int am = 0; am < 2; ++am) {
                int rA = wr * 32 + am * 16 + lm;
                int sl = (h * 4 + qk) ^ ((rA >> 1) & 7);
                af[am] = *(const s16x8*)&As[rA * 128 + sl * 8];
            }
#pragma unroll
            for (int bn = 0; bn < 2; ++bn) {
                int rB = wc * 32 + bn * 16 + lm;
                int sl = (h * 4 + qk) ^ ((rB >> 1) & 7);
                bf[bn] = *(const s16x8*)&Bs[rB * 128 + sl * 8];
            }
#pragma unroll
            for (int am = 0; am < 2; ++am)
#pragma unroll
                for (int bn = 0; bn < 2; ++bn)
                    acc[am][bn] = __builtin_amdgcn_mfma_f32_16x16x32_bf16(af[am], bf[bn], acc[am][bn], 0, 0, 0);
        }
        if (s + 1 < NS) __syncthreads();            // LDS reads done before next staging
    }

    if (!STAGE2) {
        const float* be = bias + e * DF;
        unsigned short* he = hout + (size_t)e * NTOK * DF;
#pragma unroll
        for (int am = 0; am < 2; ++am) {
#pragma unroll
            for (int bn = 0; bn < 2; ++bn) {
                int ng = n0 + wc * 32 + bn * 16 + lm;        // C/D: col = lane&15
                float bb = be[ng];
                f32x4 v = acc[am][bn];
#pragma unroll
                for (int r = 0; r < 4; ++r) {
                    int ml = wr * 32 + am * 16 + qk * 4 + r; // C/D: row = (lane>>4)*4+reg
                    int rg = m0 + ml;
                    if (rg < Ne) {
                        float tpre = v[r] + bb;
                        float g = 0.5f * tpre * (1.0f + erff(tpre * 0.70710678118654752f));
                        he[(size_t)rg * DF + ng] = f2bf(g);
                    }
                }
            }
        }
    } else {
        const float* be = bias + e * DM;
        const float* sl = sls + e * NTOK;
#pragma unroll
        for (int am = 0; am < 2; ++am) {
#pragma unroll
            for (int bn = 0; bn < 2; ++bn) {
                int ng = n0 + wc * 32 + bn * 16 + lm;
                float bb = (ksp == 0) ? be[ng] : 0.0f;       // bias added by split 0 only
                f32x4 v = acc[am][bn];
#pragma unroll
                for (int r = 0; r < 4; ++r) {
                    int ml = wr * 32 + am * 16 + qk * 4 + r;
                    int rg = m0 + ml;
                    if (rg < Ne) {
                        int tok = list[rg];
                        float s = sl[rg];
                        atomicAdd(&outp[(size_t)tok * DM + ng], s * (v[r] + bb));
                    }
                }
            }
        }
    }
}

extern "C" void kernel_launch(void* const* d_in, const int* in_sizes, int n_in,
                              void* d_out, int out_size, void* d_ws, size_t ws_size,
                              hipStream_t stream) {
    const float* x  = (const float*)d_in[0];
    const float* gw = (const float*)d_in[1];
    const float* gb = (const float*)d_in[2];
    const float* w1 = (const float*)d_in[3];
    const float* b1 = (const float*)d_in[4];
    const float* w2 = (const float*)d_in[5];
    const float* b2 = (const float*)d_in[6];
    float* out = (float*)d_out;
    char* ws = (char*)d_ws;

    // ws layout (bytes): [0] counts, [1024] lists[2][8192], [66560] sls[2][8192],
    // [262144] xb bf16[8192*1024], [+16MiB] w1t bf16[2][2048][1024],
    // [+8MiB] w2t bf16[2][1024][2048], [+8MiB] h bf16[2][8192][2048].  Total ~96.3 MB.
    int*            counts = (int*)(ws + 0);
    int*            lists  = (int*)(ws + 1024);
    float*          sls    = (float*)(ws + 1024 + 65536);
    unsigned short* xb     = (unsigned short*)(ws + 262144);
    unsigned short* w1t    = (unsigned short*)(ws + 262144 + 16777216);
    unsigned short* w2t    = (unsigned short*)(ws + 262144 + 16777216 + 8388608);
    unsigned short* hbuf   = (unsigned short*)(ws + 262144 + 16777216 + 16777216);

    hipMemsetAsync(counts, 0, 8, stream);
    prep_cvt_kernel<<<4096 + NTOK / 4, 256, 0, stream>>>(x, gw, gb, w1, w2, xb, w1t, w2t,
                                                         out, counts, lists, sls);
    // stage 1: bid = m*64 + (n_idx*2 + e); m-tiles up to NTOK/64 (ghosts exit on counts)
    moe_gemm<false><<<(NTOK / 64) * 64, 256, 0, stream>>>(xb, w1t, b1, hbuf, nullptr, counts, lists, sls);
    // stage 2: bid = m*64 + (n_idx*4 + e*2 + ksp), split-K=2
    moe_gemm<true><<<(NTOK / 64) * 64, 256, 0, stream>>>(hbuf, w2t, b2, nullptr, out, counts, lists, sls);
}

// Round 5
// 240.919 us; speedup vs baseline: 1.8763x; 1.1169x over previous
//
#include <hip/hip_runtime.h>
#include <hip/hip_bf16.h>
#include <stdint.h>

#define DM 1024
#define DF 2048
#define NTOK 8192

typedef float f32x4 __attribute__((ext_vector_type(4)));
typedef short s16x8 __attribute__((ext_vector_type(8)));   // 8 bf16 in 4 VGPRs

__device__ __forceinline__ unsigned short f2bf(float f) {
    union { float f; unsigned int u; } v; v.f = f;
    unsigned int r = v.u + 0x7fffu + ((v.u >> 16) & 1u);   // RNE
    return (unsigned short)(r >> 16);
}

// ---------------- kernel 1: fused (a) w1/w2 -> bf16 transposed, (b) zero-out + gate + x->bf16 ----------------
// blocks [0,4096): weight transpose tiles; blocks [4096,6144): gating (4 tokens/block, gw cached in LDS)
__global__ __launch_bounds__(256) void prep_cvt_kernel(const float* __restrict__ x,
                                                       const float* __restrict__ gw,
                                                       const float* __restrict__ gb,
                                                       const float* __restrict__ w1,
                                                       const float* __restrict__ w2,
                                                       unsigned short* __restrict__ xb,
                                                       unsigned short* __restrict__ w1t,
                                                       unsigned short* __restrict__ w2t,
                                                       float* __restrict__ out,
                                                       int* __restrict__ counts,
                                                       int* __restrict__ lists,
                                                       float* __restrict__ sls) {
    __shared__ __align__(16) char smem[32768];
    if (blockIdx.x < 4096) {
        // ---- weight transpose: fp32 [k][n] -> bf16 [n][k], experts {0,1} ----
        float (*tile)[65] = (float(*)[65])smem;     // 64*65*4 = 16.6 KB
        const int b = blockIdx.x;
        const int z = b >> 10;            // 0,1: w1 e0/e1 ; 2,3: w2 e0/e1
        const int rem = b & 1023;
        const int by = rem >> 5, bx = rem & 31;
        const int e = z & 1, is2 = z >> 1;
        const int R = is2 ? DF : DM;      // src rows (k)
        const int C = is2 ? DM : DF;      // src cols (n)
        const int r0 = by * 64, c0 = bx * 64;
        if (r0 >= R || c0 >= C) return;
        const float* src = is2 ? (w2 + (size_t)e * DF * DM) : (w1 + (size_t)e * DM * DF);
        unsigned short* dst = is2 ? (w2t + (size_t)e * DM * DF) : (w1t + (size_t)e * DM * DF);
        const int tc = threadIdx.x & 63;
        const int tr = threadIdx.x >> 6;
        for (int rr = tr; rr < 64; rr += 4)
            tile[rr][tc] = src[(size_t)(r0 + rr) * C + (c0 + tc)];
        __syncthreads();
        for (int rr = tr; rr < 64; rr += 4)
            dst[(size_t)(c0 + rr) * R + (r0 + tc)] = f2bf(tile[tc][rr]);
        return;
    }
    // ---- gating + zero-out + selective x->bf16 (1 wave/token, gwT in LDS) ----
    float* gwT = (float*)smem;                      // gwT[e*1024 + d], 32 KB
    const int tid = threadIdx.x;
    for (int i = 0; i < 32; ++i) {
        int flat = tid + 256 * i;                   // gw[flat]: d = flat>>3, e = flat&7
        gwT[(flat & 7) * 1024 + (flat >> 3)] = gw[flat];
    }
    __syncthreads();
    const int bid = blockIdx.x - 4096;
    const int wv = tid >> 6, lane = tid & 63;
    const int t = bid * 4 + wv;
    const float* xr = x + (size_t)t * DM;
    float* outr = out + (size_t)t * DM;
    float acc[8];
#pragma unroll
    for (int e = 0; e < 8; ++e) acc[e] = 0.f;
    float xs[16];
#pragma unroll
    for (int i = 0; i < 16; ++i) {
        const int d = i * 64 + lane;                // coalesced scalar loads
        xs[i] = xr[d];
#pragma unroll
        for (int e = 0; e < 8; ++e)                 // LDS bank = d%32 -> 2-way (free)
            acc[e] += xs[i] * gwT[e * 1024 + d];
    }
    // zero out row (float4) + store xb (scalar, coalesced)
    const float4 z4 = make_float4(0.f, 0.f, 0.f, 0.f);
#pragma unroll
    for (int i = 0; i < 4; ++i) ((float4*)outr)[i * 64 + lane] = z4;
#pragma unroll
    for (int off = 32; off > 0; off >>= 1) {
#pragma unroll
        for (int e = 0; e < 8; ++e) acc[e] += __shfl_xor(acc[e], off, 64);
    }
    float lg[8];
#pragma unroll
    for (int e = 0; e < 8; ++e) lg[e] = acc[e] + gb[e];
    int b1i = 0; float b1v = lg[0];
#pragma unroll
    for (int e = 1; e < 8; ++e) if (lg[e] > b1v) { b1v = lg[e]; b1i = e; }
    int b2i = -1; float b2v = -3.4e38f;
#pragma unroll
    for (int e = 0; e < 8; ++e) if (e != b1i && lg[e] > b2v) { b2v = lg[e]; b2i = e; }
    const bool sel = (b1i == 0) || (b2i == 1);
    if (sel) {        // only selected tokens are ever gathered by the GEMMs
        unsigned short* xbr = xb + (size_t)t * DM;
#pragma unroll
        for (int i = 0; i < 16; ++i) xbr[i * 64 + lane] = f2bf(xs[i]);
    }
    if (lane == 0) {
        float den = 0.f;
#pragma unroll
        for (int e = 0; e < 8; ++e) den += expf(lg[e] - b1v);
        if (b1i == 0) {                       // top-1 slot matches expert 0
            float s0 = expf(lg[0] - b1v) / den;
            int p = atomicAdd(&counts[0], 1);
            lists[p] = t; sls[p] = s0;
        }
        if (b2i == 1) {                       // top-2 slot matches expert 1
            float s1 = expf(lg[1] - b1v) / den;
            int p = atomicAdd(&counts[1], 1);
            lists[NTOK + p] = t; sls[NTOK + p] = s1;
        }
    }
    if (bid == 0 && tid == 0) out[(size_t)NTOK * DM] = 0.0f;   // lbl == 0 exactly
}

// ---------------- kernels 2/3: MFMA GEMM, 64x64 tile, BK=64, reg-prefetch double buffer ----------------
// Pipeline: global->VGPR loads for tile s+1 issue BEFORE compute of tile s (in flight through
// the MFMAs); ds_write waits on them only after barrier 1. Named scalars, no arrays/lambdas
// (R3's array-in-lambda structure spilled prefetch regs to scratch: VGPR=32, WRITE +107MB).
// LDS: row stride 80 bf16 (160 B) + chunk slot = q ^ (row&7): frag reads and writes <=2-way.
// STAGE2=false: h = gelu(Xg @ W1 + b1) -> hout (bf16 [e][NTOK][DF])
// STAGE2=true : out[tok] += scale * (h @ W2 + b2), split-K=2, fp32 atomicAdd scatter
template <bool STAGE2>
__global__ __launch_bounds__(256, 4) void moe_gemm(const unsigned short* __restrict__ Aglob,
                                                   const unsigned short* __restrict__ Bglob,
                                                   const float* __restrict__ bias,
                                                   unsigned short* __restrict__ hout,
                                                   float* __restrict__ outp,
                                                   const int* __restrict__ counts,
                                                   const int* __restrict__ lists,
                                                   const float* __restrict__ sls) {
    constexpr int KTOT = STAGE2 ? DF : DM;
    constexpr int KS = STAGE2 ? KTOT / 2 : KTOT;   // split-K=2 on stage 2
    constexpr int NS = KS / 64;                    // 16 k-steps
    constexpr int RS = 80;                         // LDS row stride in bf16
    const int bid = blockIdx.x;
    const int g = bid & 63;
    const int m0 = (bid >> 6) * 64;
    const int n_idx = STAGE2 ? (g >> 2) : (g >> 1);
    const int e     = STAGE2 ? ((g >> 1) & 1) : (g & 1);
    const int ksp   = STAGE2 ? (g & 1) : 0;
    const int Ne = counts[e];
    if (m0 >= Ne) return;
    const int n0 = n_idx * 64;
    const int k0 = ksp * KS;
    const int tid = threadIdx.x;
    const int lane = tid & 63, wv = tid >> 6;
    const int wr = wv >> 1, wc = wv & 1;           // 2x2 wave grid; wave owns 32x32
    const int lm = lane & 15, qk = lane >> 4;

    const int* list = lists + e * NTOK;
    const unsigned short* Ae = STAGE2 ? (Aglob + (size_t)e * NTOK * DF) : Aglob;
    const unsigned short* Be = Bglob + (size_t)e * DM * DF;

    __shared__ alignas(16) unsigned short As[64 * RS];   // 10 KB
    __shared__ alignas(16) unsigned short Bs[64 * RS];   // 10 KB

    // staging map: chunk c (0..511) -> row c>>3, q = c&7; LDS slot = q ^ (row&7)
    const int rowL0 = tid >> 3,          qL0 = tid & 7;
    const int rowL1 = (tid + 256) >> 3,  qL1 = tid & 7;      // (tid+256)&7 == tid&7
    const int ofs0 = rowL0 * RS + (qL0 ^ (rowL0 & 7)) * 8;
    const int ofs1 = rowL1 * RS + (qL1 ^ (rowL1 & 7)) * 8;
    int rgA0 = m0 + rowL0; if (rgA0 >= Ne) rgA0 = m0;        // clamp: epilogue-guarded
    int rgA1 = m0 + rowL1; if (rgA1 >= Ne) rgA1 = m0;
    const size_t arow0 = STAGE2 ? (size_t)rgA0 * KTOT : (size_t)list[rgA0] * KTOT;
    const size_t arow1 = STAGE2 ? (size_t)rgA1 * KTOT : (size_t)list[rgA1] * KTOT;
    const unsigned short* sa0 = Ae + arow0 + k0 + qL0 * 8;
    const unsigned short* sa1 = Ae + arow1 + k0 + qL1 * 8;
    const unsigned short* sb0 = Be + (size_t)(n0 + rowL0) * KTOT + k0 + qL0 * 8;
    const unsigned short* sb1 = Be + (size_t)(n0 + rowL1) * KTOT + k0 + qL1 * 8;

    f32x4 acc00 = {0.f,0.f,0.f,0.f}, acc01 = acc00, acc10 = acc00, acc11 = acc00;

    // frag read offsets (bf16 elems): row rA*RS + (chunk ^ (rA&7))*8, chunk = h*4+qk
    const int rA0 = wr * 32 + lm,      rA1 = rA0 + 16;
    const int rB0 = wc * 32 + lm,      rB1 = rB0 + 16;

    // prologue: tile 0 -> regs -> LDS
    uint4 pa0 = *(const uint4*)sa0; sa0 += 64;
    uint4 pa1 = *(const uint4*)sa1; sa1 += 64;
    uint4 pb0 = *(const uint4*)sb0; sb0 += 64;
    uint4 pb1 = *(const uint4*)sb1; sb1 += 64;
    *(uint4*)&As[ofs0] = pa0;  *(uint4*)&As[ofs1] = pa1;
    *(uint4*)&Bs[ofs0] = pb0;  *(uint4*)&Bs[ofs1] = pb1;
    __syncthreads();

#pragma unroll 1
    for (int s = 0; s < NS; ++s) {
        const bool pre = (s + 1 < NS);
        if (pre) {                                   // prefetch tile s+1 (in flight during MFMA)
            pa0 = *(const uint4*)sa0; sa0 += 64;
            pa1 = *(const uint4*)sa1; sa1 += 64;
            pb0 = *(const uint4*)sb0; sb0 += 64;
            pb1 = *(const uint4*)sb1; sb1 += 64;
        }
#pragma unroll
        for (int h = 0; h < 2; ++h) {                // two 16x16x32 k-slices of BK=64
            const int c = h * 4 + qk;
            s16x8 af0 = *(const s16x8*)&As[rA0 * RS + ((c ^ (rA0 & 7)) * 8)];
            s16x8 af1 = *(const s16x8*)&As[rA1 * RS + ((c ^ (rA1 & 7)) * 8)];
            s16x8 bf0 = *(const s16x8*)&Bs[rB0 * RS + ((c ^ (rB0 & 7)) * 8)];
            s16x8 bf1 = *(const s16x8*)&Bs[rB1 * RS + ((c ^ (rB1 & 7)) * 8)];
            acc00 = __builtin_amdgcn_mfma_f32_16x16x32_bf16(af0, bf0, acc00, 0, 0, 0);
            acc01 = __builtin_amdgcn_mfma_f32_16x16x32_bf16(af0, bf1, acc01, 0, 0, 0);
            acc10 = __builtin_amdgcn_mfma_f32_16x16x32_bf16(af1, bf0, acc10, 0, 0, 0);
            acc11 = __builtin_amdgcn_mfma_f32_16x16x32_bf16(af1, bf1, acc11, 0, 0, 0);
        }
        if (pre) {
            __syncthreads();                         // all waves done reading LDS
            *(uint4*)&As[ofs0] = pa0;  *(uint4*)&As[ofs1] = pa1;
            *(uint4*)&Bs[ofs0] = pb0;  *(uint4*)&Bs[ofs1] = pb1;
            __syncthreads();                         // staging visible
        }
    }

    // epilogue: C/D layout col = lane&15, row = (lane>>4)*4 + reg
    f32x4 accs[2][2] = {{acc00, acc01}, {acc10, acc11}};
    if (!STAGE2) {
        const float* be = bias + e * DF;
        unsigned short* he = hout + (size_t)e * NTOK * DF;
#pragma unroll
        for (int am = 0; am < 2; ++am) {
#pragma unroll
            for (int bn = 0; bn < 2; ++bn) {
                int ng = n0 + wc * 32 + bn * 16 + lm;
                float bb = be[ng];
                f32x4 v = accs[am][bn];
#pragma unroll
                for (int r = 0; r < 4; ++r) {
                    int ml = wr * 32 + am * 16 + qk * 4 + r;
                    int rg = m0 + ml;
                    if (rg < Ne) {
                        float tpre = v[r] + bb;
                        float gl = 0.5f * tpre * (1.0f + erff(tpre * 0.70710678118654752f));
                        he[(size_t)rg * DF + ng] = f2bf(gl);
                    }
                }
            }
        }
    } else {
        const float* be = bias + e * DM;
        const float* sl = sls + e * NTOK;
#pragma unroll
        for (int am = 0; am < 2; ++am) {
#pragma unroll
            for (int bn = 0; bn < 2; ++bn) {
                int ng = n0 + wc * 32 + bn * 16 + lm;
                float bb = (ksp == 0) ? be[ng] : 0.0f;       // bias added by split 0 only
                f32x4 v = accs[am][bn];
#pragma unroll
                for (int r = 0; r < 4; ++r) {
                    int ml = wr * 32 + am * 16 + qk * 4 + r;
                    int rg = m0 + ml;
                    if (rg < Ne) {
                        int tok = list[rg];
                        float s = sl[rg];
                        atomicAdd(&outp[(size_t)tok * DM + ng], s * (v[r] + bb));
                    }
                }
            }
        }
    }
}

extern "C" void kernel_launch(void* const* d_in, const int* in_sizes, int n_in,
                              void* d_out, int out_size, void* d_ws, size_t ws_size,
                              hipStream_t stream) {
    const float* x  = (const float*)d_in[0];
    const float* gw = (const float*)d_in[1];
    const float* gb = (const float*)d_in[2];
    const float* w1 = (const float*)d_in[3];
    const float* b1 = (const float*)d_in[4];
    const float* w2 = (const float*)d_in[5];
    const float* b2 = (const float*)d_in[6];
    float* out = (float*)d_out;
    char* ws = (char*)d_ws;

    // ws layout (bytes): [0] counts, [1024] lists[2][8192], [66560] sls[2][8192],
    // [262144] xb bf16[8192*1024], [+16MiB] w1t bf16[2][2048][1024],
    // [+8MiB] w2t bf16[2][1024][2048], [+8MiB] h bf16[2][8192][2048].  Total ~96.3 MB.
    int*            counts = (int*)(ws + 0);
    int*            lists  = (int*)(ws + 1024);
    float*          sls    = (float*)(ws + 1024 + 65536);
    unsigned short* xb     = (unsigned short*)(ws + 262144);
    unsigned short* w1t    = (unsigned short*)(ws + 262144 + 16777216);
    unsigned short* w2t    = (unsigned short*)(ws + 262144 + 16777216 + 8388608);
    unsigned short* hbuf   = (unsigned short*)(ws + 262144 + 16777216 + 16777216);

    hipMemsetAsync(counts, 0, 8, stream);
    prep_cvt_kernel<<<4096 + NTOK / 4, 256, 0, stream>>>(x, gw, gb, w1, w2, xb, w1t, w2t,
                                                         out, counts, lists, sls);
    // stage 1: bid = m*64 + (n_idx*2 + e); m-tiles up to NTOK/64 (ghosts exit on counts)
    moe_gemm<false><<<(NTOK / 64) * 64, 256, 0, stream>>>(xb, w1t, b1, hbuf, nullptr, counts, lists, sls);
    // stage 2: bid = m*64 + (n_idx*4 + e*2 + ksp), split-K=2
    moe_gemm<true><<<(NTOK / 64) * 64, 256, 0, stream>>>(hbuf, w2t, b2, nullptr, out, counts, lists, sls);
}